// Round 3
// baseline (729.332 us; speedup 1.0000x reference)
//
#include <hip/hip_runtime.h>

#define NPOS   65536      // 16*16*16*16 positions
#define CDIM   256
#define KCODES 512
#define ZTOT   16777216   // 16*256*16*16*16
#define IDX_OFF (ZTOT + 1)

// ws layout: ws[0] = loss accumulator (float); ws[64..64+512) = cb_sq_np[k] (f32)

// numpy pairwise sum replication, f32, contraction-proof:
// sum256(a) = pw128(a) + pw128(a+128)
// pw128: r[j]=a[j]; for i=8..120 step 8: r[j]+=a[i+j];
//        res = ((r0+r1)+(r2+r3)) + ((r4+r5)+(r6+r7))
__device__ __forceinline__ float np_pw128_sq(const float* __restrict__ a) {
    float r[8];
    #pragma unroll
    for (int j = 0; j < 8; ++j) r[j] = __fmul_rn(a[j], a[j]);
    #pragma unroll 1
    for (int i = 8; i < 128; i += 8) {
        #pragma unroll
        for (int j = 0; j < 8; ++j)
            r[j] = __fadd_rn(r[j], __fmul_rn(a[i + j], a[i + j]));
    }
    return __fadd_rn(__fadd_rn(__fadd_rn(r[0], r[1]), __fadd_rn(r[2], r[3])),
                     __fadd_rn(__fadd_rn(r[4], r[5]), __fadd_rn(r[6], r[7])));
}

__global__ void vq_prep(const float* __restrict__ cb, float* __restrict__ ws) {
    int k = threadIdx.x;            // 512 threads, 1 block
    if (k == 0) ws[0] = 0.0f;
    const float* row = cb + k * CDIM;
    ws[64 + k] = __fadd_rn(np_pw128_sq(row), np_pw128_sq(row + 128));
}

// grid: NPOS/64 = 1024 blocks, 256 threads.
// thread t: p = t&63 (position lane), cg = t>>6 (channel quarter, wave-uniform)
__launch_bounds__(256, 2)
__global__ void vq_argmin(const float* __restrict__ z,
                          const float* __restrict__ cb,
                          const float* __restrict__ ws,
                          float* __restrict__ out) {
    const int t  = threadIdx.x;
    const int p  = t & 63;
    const int cg = t >> 6;
    const int n  = blockIdx.x * 64 + p;
    const int b  = n >> 12;          // 4096 positions per batch
    const int s  = n & 4095;
    const float* zbase = z + (size_t)b * 1048576 + s;   // + c*4096

    // my 64 channels in registers
    float zr[64];
    #pragma unroll
    for (int cc = 0; cc < 64; ++cc)
        zr[cc] = zbase[(size_t)(cg * 64 + cc) * 4096];

    __shared__ float  cbT[256 * 16];      // [c][j], 16 KB
    __shared__ double redd[4 * 64 * 17];  // [cg][p][17] padded, 34.8 KB
    __shared__ float  cbsq_s[KCODES];     // 2 KB
    __shared__ float  pre[2][64][9];      // pairwise prefixes / final argmin
    __shared__ float  blk[2][64];         // per-128-block pairwise results

    cbsq_s[t]       = ws[64 + t];
    cbsq_s[256 + t] = ws[64 + 256 + t];

    // ---- replicate numpy f32 z_sq = pw128(ch 0..127) + pw128(ch 128..255) ----
    // accumulator chain r[j] = a[j] + a[j+8] + ... + a[j+120] (sequential).
    // cg0 (ch 0..63) / cg2 (ch 128..191) compute the first 8 terms (prefix);
    // cg1 (ch 64..127) / cg3 (ch 192..255) continue the chain in order.
    if ((cg & 1) == 0) {
        const int g = cg >> 1;
        #pragma unroll
        for (int j = 0; j < 8; ++j) {
            float r = __fmul_rn(zr[j], zr[j]);
            #pragma unroll
            for (int m = 1; m < 8; ++m)
                r = __fadd_rn(r, __fmul_rn(zr[j + 8 * m], zr[j + 8 * m]));
            pre[g][p][j] = r;
        }
    }
    __syncthreads();
    if (cg & 1) {
        const int g = cg >> 1;
        float r[8];
        #pragma unroll
        for (int j = 0; j < 8; ++j) {
            float v = pre[g][p][j];
            #pragma unroll
            for (int m = 0; m < 8; ++m)
                v = __fadd_rn(v, __fmul_rn(zr[j + 8 * m], zr[j + 8 * m]));
            r[j] = v;
        }
        blk[g][p] = __fadd_rn(__fadd_rn(__fadd_rn(r[0], r[1]), __fadd_rn(r[2], r[3])),
                              __fadd_rn(__fadd_rn(r[4], r[5]), __fadd_rn(r[6], r[7])));
    }
    __syncthreads();
    const float zsq = __fadd_rn(blk[0][p], blk[1][p]);

    float bestv = 3.4e38f;
    int   besti = 0;

    const int sj = t & 15, sc = t >> 4;  // staging role

    #pragma unroll 1
    for (int ck = 0; ck < 32; ++ck) {
        const int k0 = ck * 16;
        __syncthreads();
        // stage cb[k0..k0+16)[0..256) transposed into cbT[c][j]
        {
            const float4* src = (const float4*)(cb + (size_t)(k0 + sj) * CDIM + sc * 16);
            #pragma unroll
            for (int q = 0; q < 4; ++q) {
                float4 v = src[q];
                cbT[(sc * 16 + q * 4 + 0) * 16 + sj] = v.x;
                cbT[(sc * 16 + q * 4 + 1) * 16 + sj] = v.y;
                cbT[(sc * 16 + q * 4 + 2) * 16 + sj] = v.z;
                cbT[(sc * 16 + q * 4 + 3) * 16 + sj] = v.w;
            }
        }
        __syncthreads();

        // f64 partial dot over my 64 channels
        double dacc[16];
        #pragma unroll
        for (int j = 0; j < 16; ++j) dacc[j] = 0.0;

        #pragma unroll 4
        for (int cc = 0; cc < 64; ++cc) {
            const double zd = (double)zr[cc];
            const float4* row = (const float4*)&cbT[(cg * 64 + cc) * 16];
            #pragma unroll
            for (int q = 0; q < 4; ++q) {
                float4 v = row[q];   // wave-uniform address -> LDS broadcast
                dacc[q * 4 + 0] += zd * (double)v.x;
                dacc[q * 4 + 1] += zd * (double)v.y;
                dacc[q * 4 + 2] += zd * (double)v.z;
                dacc[q * 4 + 3] += zd * (double)v.w;
            }
        }

        #pragma unroll
        for (int j = 0; j < 16; ++j)
            redd[(cg * 64 + p) * 17 + j] = dacc[j];
        __syncthreads();

        // np-replica distance: fl32(fl32(zsq + cbsq) - 2*fl32(dot))
        #pragma unroll
        for (int jj = 0; jj < 4; ++jj) {
            const int j = cg * 4 + jj;
            double d = (redd[(0 * 64 + p) * 17 + j] + redd[(1 * 64 + p) * 17 + j])
                     + (redd[(2 * 64 + p) * 17 + j] + redd[(3 * 64 + p) * 17 + j]);
            const int k = k0 + j;
            float dotf = (float)d;
            float dist = __fsub_rn(__fadd_rn(zsq, cbsq_s[k]), __fmul_rn(2.0f, dotf));
            if (dist < bestv) { bestv = dist; besti = k; }
        }
    }

    // final cross-cg argmin with np tie-break (lowest index)
    __syncthreads();
    pre[0][p][cg] = bestv;
    pre[1][p][cg] = __int_as_float(besti);
    __syncthreads();
    if (cg == 0) {
        float bv = pre[0][p][0];
        int   bi = __float_as_int(pre[1][p][0]);
        #pragma unroll
        for (int g = 1; g < 4; ++g) {
            float v = pre[0][p][g];
            int   i = __float_as_int(pre[1][p][g]);
            if (v < bv || (v == bv && i < bi)) { bv = v; bi = i; }
        }
        out[IDX_OFF + n] = (float)bi;   // encoding_indices written as float
    }
}

// z_q gather + squared-error partial sums. grid-stride, coalesced in flat index.
__global__ void vq_gather(const float* __restrict__ z,
                          const float* __restrict__ cb,
                          float* __restrict__ out,
                          float* __restrict__ loss_acc) {
    const float* idxf = out + IDX_OFF;
    const int stride = gridDim.x * blockDim.x;
    float acc = 0.0f;
    for (int o = blockIdx.x * blockDim.x + threadIdx.x; o < ZTOT; o += stride) {
        int c = (o >> 12) & 255;
        int n = ((o >> 20) << 12) | (o & 4095);
        int idx = (int)idxf[n];
        float v  = cb[idx * CDIM + c];
        float zv = z[o];
        out[o] = v;
        float df = v - zv;
        acc += df * df;
    }
    #pragma unroll
    for (int off = 32; off > 0; off >>= 1)
        acc += __shfl_down(acc, off, 64);
    __shared__ float wsum[4];
    int lane = threadIdx.x & 63, wid = threadIdx.x >> 6;
    if (lane == 0) wsum[wid] = acc;
    __syncthreads();
    if (threadIdx.x == 0) {
        float bsum = wsum[0] + wsum[1] + wsum[2] + wsum[3];
        atomicAdd(loss_acc, bsum);
    }
}

__global__ void vq_fin(const float* __restrict__ ws, float* __restrict__ out) {
    if (threadIdx.x == 0)
        out[ZTOT] = 1.25f * ws[0] / (float)ZTOT;
}

extern "C" void kernel_launch(void* const* d_in, const int* in_sizes, int n_in,
                              void* d_out, int out_size, void* d_ws, size_t ws_size,
                              hipStream_t stream) {
    const float* z  = (const float*)d_in[0];
    const float* cb = (const float*)d_in[1];
    float* out = (float*)d_out;
    float* ws  = (float*)d_ws;

    vq_prep<<<1, 512, 0, stream>>>(cb, ws);
    vq_argmin<<<NPOS / 64, 256, 0, stream>>>(z, cb, ws, out);
    vq_gather<<<2048, 256, 0, stream>>>(z, cb, out, ws);
    vq_fin<<<1, 64, 0, stream>>>(ws, out);
}

// Round 4
// 441.903 us; speedup vs baseline: 1.6504x; 1.6504x over previous
//
#include <hip/hip_runtime.h>

#define NPOS   65536      // 16*16*16*16 positions
#define CDIM   256
#define KCODES 512
#define ZTOT   16777216   // 16*256*16*16*16
#define IDX_OFF (ZTOT + 1)
#define TAU    2.0e-3f

// ws layout (float idx): [0]=loss acc; int[1]=refine count; [64..576)=cb_sq f32;
// int[576..66112)=refine row list; [66112..131648) = cb bf16 (ushort[131072])
#define WS_CBSQ 64
#define WS_LIST 576
#define WS_CBBF 66112

using bf16x8 = __attribute__((ext_vector_type(8))) short;
using f32x4  = __attribute__((ext_vector_type(4))) float;

__device__ __forceinline__ unsigned short f2bf(float f) {
    unsigned int u = __float_as_uint(f);
    return (unsigned short)((u + 0x7fffu + ((u >> 16) & 1u)) >> 16);
}

// numpy pairwise sum-of-squares, f32, contraction-proof (verified r3)
__device__ __forceinline__ float np_pw128_sq(const float* __restrict__ a) {
    float r[8];
    #pragma unroll
    for (int j = 0; j < 8; ++j) r[j] = __fmul_rn(a[j], a[j]);
    #pragma unroll 1
    for (int i = 8; i < 128; i += 8) {
        #pragma unroll
        for (int j = 0; j < 8; ++j)
            r[j] = __fadd_rn(r[j], __fmul_rn(a[i + j], a[i + j]));
    }
    return __fadd_rn(__fadd_rn(__fadd_rn(r[0], r[1]), __fadd_rn(r[2], r[3])),
                     __fadd_rn(__fadd_rn(r[4], r[5]), __fadd_rn(r[6], r[7])));
}

__global__ void vq_prep(const float* __restrict__ cb, float* __restrict__ ws) {
    int k = threadIdx.x;            // 512 threads, 1 block
    if (k == 0) { ws[0] = 0.0f; ((int*)ws)[1] = 0; }
    const float* row = cb + k * CDIM;
    ws[WS_CBSQ + k] = __fadd_rn(np_pw128_sq(row), np_pw128_sq(row + 128));
}

__global__ void vq_cvt(const float* __restrict__ cb, float* __restrict__ ws) {
    unsigned short* cbbf = (unsigned short*)(ws + WS_CBBF);
    int i = blockIdx.x * 256 + threadIdx.x;     // 512 blocks x 256
    cbbf[i] = f2bf(cb[i]);
}

// Screening: s[k] = cbsq[k] - 2*dot_bf16. Block = 32 rows x 512 codes.
// 4 waves split codes (128 each). MFMA 16x16x32 bf16; A row = l&15,
// k = 8*(l>>4)+j (A/B consistent => k-permutation safe); C col=l&15,
// row=(l>>4)*4+reg (m89-verified).
__launch_bounds__(256, 2)
__global__ void vq_screen(const float* __restrict__ z,
                          float* __restrict__ ws,
                          float* __restrict__ out) {
    const int t  = threadIdx.x;
    const int w  = t >> 6;          // wave id: codes [w*128, w*128+128)
    const int l  = t & 63;
    const int g  = l >> 4;
    const int c0 = l & 15;
    const int m0 = blockIdx.x * 32;
    const int b  = m0 >> 12;
    const int s0 = m0 & 4095;
    const float* zb = z + (size_t)b * 1048576 + s0;
    const unsigned short* cbbf = (const unsigned short*)(ws + WS_CBBF);
    int* wsi = (int*)ws;

    __shared__ float cbsq_s[KCODES];
    __shared__ float red[4 * 32 * 4];    // [w][row][v1,i1,v2,pad]
    cbsq_s[t]       = ws[WS_CBSQ + t];
    cbsq_s[256 + t] = ws[WS_CBSQ + 256 + t];

    // A-fragments: 2 m-tiles x 8 k-steps, 8 scalar f32 loads each -> bf16
    bf16x8 afr[2][8];
    #pragma unroll
    for (int mt = 0; mt < 2; ++mt) {
        #pragma unroll
        for (int kt = 0; kt < 8; ++kt) {
            const float* ap = zb + (mt * 16 + c0) + (size_t)(kt * 32 + g * 8) * 4096;
            bf16x8 a;
            #pragma unroll
            for (int j = 0; j < 8; ++j)
                a[j] = (short)f2bf(ap[(size_t)j * 4096]);
            afr[mt][kt] = a;
        }
    }

    f32x4 acc[2][8];
    #pragma unroll
    for (int mt = 0; mt < 2; ++mt)
        #pragma unroll
        for (int nt = 0; nt < 8; ++nt)
            acc[mt][nt] = (f32x4){0.f, 0.f, 0.f, 0.f};

    // B-fragments from L2 (codebook bf16, 256 KB hot), double-buffered
    bf16x8 bfr[2][8];
    #pragma unroll
    for (int kt = 0; kt < 8; ++kt)
        bfr[0][kt] = *(const bf16x8*)(cbbf + (size_t)(w * 128 + c0) * 256 + kt * 32 + g * 8);

    #pragma unroll
    for (int nt = 0; nt < 8; ++nt) {
        const int cur = nt & 1;
        if (nt < 7) {
            #pragma unroll
            for (int kt = 0; kt < 8; ++kt)
                bfr[cur ^ 1][kt] = *(const bf16x8*)(cbbf +
                    (size_t)(w * 128 + (nt + 1) * 16 + c0) * 256 + kt * 32 + g * 8);
        }
        #pragma unroll
        for (int kt = 0; kt < 8; ++kt) {
            acc[0][nt] = __builtin_amdgcn_mfma_f32_16x16x32_bf16(afr[0][kt], bfr[cur][kt], acc[0][nt], 0, 0, 0);
            acc[1][nt] = __builtin_amdgcn_mfma_f32_16x16x32_bf16(afr[1][kt], bfr[cur][kt], acc[1][nt], 0, 0, 0);
        }
    }

    __syncthreads();   // cbsq_s ready; also fence before red[] use

    // per-lane best2 per row, then merge across the 16-lane col group
    #pragma unroll
    for (int mt = 0; mt < 2; ++mt) {
        #pragma unroll
        for (int reg = 0; reg < 4; ++reg) {
            const int row = mt * 16 + g * 4 + reg;
            float v1 = 3.4028235e38f, v2 = 3.4028235e38f;
            int   i1 = 0x7fffffff;
            #pragma unroll
            for (int nt = 0; nt < 8; ++nt) {
                const int k = w * 128 + nt * 16 + c0;
                const float s = fmaf(-2.0f, acc[mt][nt][reg], cbsq_s[k]);
                if (s < v1 || (s == v1 && k < i1)) { v2 = v1; v1 = s; i1 = k; }
                else v2 = fminf(v2, s);
            }
            #pragma unroll
            for (int m = 1; m < 16; m <<= 1) {
                float pv1 = __shfl_xor(v1, m, 64);
                int   pi1 = __shfl_xor(i1, m, 64);
                float pv2 = __shfl_xor(v2, m, 64);
                if (pv1 < v1 || (pv1 == v1 && pi1 < i1)) {
                    v2 = fminf(v1, pv2); v1 = pv1; i1 = pi1;
                } else {
                    v2 = fminf(v2, pv1);
                }
            }
            if (c0 == 0) {
                float* rp = &red[(w * 32 + row) * 4];
                rp[0] = v1; rp[1] = __int_as_float(i1); rp[2] = v2;
            }
        }
    }
    __syncthreads();

    if (t < 32) {
        float v1 = red[(0 * 32 + t) * 4 + 0];
        int   i1 = __float_as_int(red[(0 * 32 + t) * 4 + 1]);
        float v2 = red[(0 * 32 + t) * 4 + 2];
        #pragma unroll
        for (int ww = 1; ww < 4; ++ww) {
            float pv1 = red[(ww * 32 + t) * 4 + 0];
            int   pi1 = __float_as_int(red[(ww * 32 + t) * 4 + 1]);
            float pv2 = red[(ww * 32 + t) * 4 + 2];
            if (pv1 < v1 || (pv1 == v1 && pi1 < i1)) {
                v2 = fminf(v1, pv2); v1 = pv1; i1 = pi1;
            } else {
                v2 = fminf(v2, pv1);
            }
        }
        const int n = m0 + t;
        out[IDX_OFF + n] = (float)i1;            // provisional if flagged
        if (v2 - v1 < TAU) {
            int pos = atomicAdd(wsi + 1, 1);
            wsi[WS_LIST + pos] = n;
        }
    }
}

// Exact np-replica re-evaluation of flagged rows, 8 rows per block iteration.
__global__ void vq_refine(const float* __restrict__ z,
                          const float* __restrict__ cb,
                          float* __restrict__ ws,
                          float* __restrict__ out) {
    const int* wsi = (const int*)ws;
    const int cnt = wsi[1];
    const int t = threadIdx.x;

    __shared__ float zs[8][264];    // 264: keeps float4 rows 16B-aligned
    __shared__ float zsqs[8];
    __shared__ int   rows[8];
    __shared__ float dv[8][256];
    __shared__ int   di[8][256];

    for (int g0 = blockIdx.x * 8; g0 < cnt; g0 += gridDim.x * 8) {
        __syncthreads();
        if (t < 8) rows[t] = (g0 + t < cnt) ? wsi[WS_LIST + g0 + t] : -1;
        __syncthreads();
        #pragma unroll
        for (int r = 0; r < 8; ++r) {
            int n = rows[r];
            if (n >= 0)
                zs[r][t] = z[(size_t)(n >> 12) * 1048576 + (size_t)t * 4096 + (n & 4095)];
        }
        __syncthreads();
        if (t < 8 && rows[t] >= 0)
            zsqs[t] = __fadd_rn(np_pw128_sq(&zs[t][0]), np_pw128_sq(&zs[t][128]));
        __syncthreads();

        // thread t evaluates codes t and t+256 for all 8 rows, f64 dot
        double d0[8], d1[8];
        #pragma unroll
        for (int r = 0; r < 8; ++r) { d0[r] = 0.0; d1[r] = 0.0; }
        const float* c0p = cb + (size_t)t * CDIM;
        const float* c1p = cb + (size_t)(t + 256) * CDIM;
        #pragma unroll 1
        for (int c4 = 0; c4 < 64; ++c4) {
            float4 e0 = *(const float4*)(c0p + c4 * 4);
            float4 e1 = *(const float4*)(c1p + c4 * 4);
            #pragma unroll
            for (int r = 0; r < 8; ++r) {
                float4 zv = *(const float4*)(&zs[r][c4 * 4]);
                d0[r] += (double)e0.x * (double)zv.x + (double)e0.y * (double)zv.y
                       + (double)e0.z * (double)zv.z + (double)e0.w * (double)zv.w;
                d1[r] += (double)e1.x * (double)zv.x + (double)e1.y * (double)zv.y
                       + (double)e1.z * (double)zv.z + (double)e1.w * (double)zv.w;
            }
        }
        const float cq0 = ws[WS_CBSQ + t];
        const float cq1 = ws[WS_CBSQ + t + 256];
        #pragma unroll
        for (int r = 0; r < 8; ++r) {
            float da = __fsub_rn(__fadd_rn(zsqs[r], cq0), __fmul_rn(2.0f, (float)d0[r]));
            float db = __fsub_rn(__fadd_rn(zsqs[r], cq1), __fmul_rn(2.0f, (float)d1[r]));
            if (db < da) { dv[r][t] = db; di[r][t] = t + 256; }
            else         { dv[r][t] = da; di[r][t] = t; }
        }
        for (int off = 128; off > 0; off >>= 1) {
            __syncthreads();
            if (t < off) {
                #pragma unroll
                for (int r = 0; r < 8; ++r) {
                    float va = dv[r][t], vb = dv[r][t + off];
                    int   ia = di[r][t], ib = di[r][t + off];
                    if (vb < va || (vb == va && ib < ia)) { dv[r][t] = vb; di[r][t] = ib; }
                }
            }
        }
        __syncthreads();
        if (t < 8 && rows[t] >= 0)
            out[IDX_OFF + rows[t]] = (float)di[t][0];
    }
}

// z_q gather + squared-error partial sums (verified r3)
__global__ void vq_gather(const float* __restrict__ z,
                          const float* __restrict__ cb,
                          float* __restrict__ out,
                          float* __restrict__ loss_acc) {
    const float* idxf = out + IDX_OFF;
    const int stride = gridDim.x * blockDim.x;
    float acc = 0.0f;
    for (int o = blockIdx.x * blockDim.x + threadIdx.x; o < ZTOT; o += stride) {
        int c = (o >> 12) & 255;
        int n = ((o >> 20) << 12) | (o & 4095);
        int idx = (int)idxf[n];
        float v  = cb[idx * CDIM + c];
        float zv = z[o];
        out[o] = v;
        float df = v - zv;
        acc += df * df;
    }
    #pragma unroll
    for (int off = 32; off > 0; off >>= 1)
        acc += __shfl_down(acc, off, 64);
    __shared__ float wsum[4];
    int lane = threadIdx.x & 63, wid = threadIdx.x >> 6;
    if (lane == 0) wsum[wid] = acc;
    __syncthreads();
    if (threadIdx.x == 0) {
        float bsum = wsum[0] + wsum[1] + wsum[2] + wsum[3];
        atomicAdd(loss_acc, bsum);
    }
}

__global__ void vq_fin(const float* __restrict__ ws, float* __restrict__ out) {
    if (threadIdx.x == 0)
        out[ZTOT] = 1.25f * ws[0] / (float)ZTOT;
}

extern "C" void kernel_launch(void* const* d_in, const int* in_sizes, int n_in,
                              void* d_out, int out_size, void* d_ws, size_t ws_size,
                              hipStream_t stream) {
    const float* z  = (const float*)d_in[0];
    const float* cb = (const float*)d_in[1];
    float* out = (float*)d_out;
    float* ws  = (float*)d_ws;

    vq_prep<<<1, 512, 0, stream>>>(cb, ws);
    vq_cvt<<<512, 256, 0, stream>>>(cb, ws);
    vq_screen<<<NPOS / 32, 256, 0, stream>>>(z, ws, out);
    vq_refine<<<256, 256, 0, stream>>>(z, cb, ws, out);
    vq_gather<<<2048, 256, 0, stream>>>(z, cb, out, ws);
    vq_fin<<<1, 64, 0, stream>>>(ws, out);
}